// Round 1
// baseline (185.775 us; speedup 1.0000x reference)
//
#include <hip/hip_runtime.h>
#include <cstdint>

// HypHawkes: attn = project(expmap0(softmax((project(expmap0(q))@W.T) @ project(expmap0(ctx)).T / d)))
// Pipeline: rownorm(q)->bf16, rownorm(ctx)->bf16, W->bf16, gemm_bt(bf16 out),
//           gemm_bt(fp32 scores into d_out), in-place softmax+expmap+project.

typedef unsigned short ushort_t;
typedef __bf16 bf16x8 __attribute__((ext_vector_type(8)));
typedef float f32x4 __attribute__((ext_vector_type(4)));

__device__ __forceinline__ unsigned short f32_to_bf16(float f) {
  unsigned int u = __float_as_uint(f);
  u = (u + 0x7fffu + ((u >> 16) & 1u)) >> 16;  // RNE; inputs are finite
  return (unsigned short)u;
}

__device__ __forceinline__ void async_copy16(const void* g, void* s) {
  __builtin_amdgcn_global_load_lds(
      (const __attribute__((address_space(1))) void*)g,
      (__attribute__((address_space(3))) void*)s, 16, 0, 0);
}

// ---------------- row normalize + expmap0 + project, fp32 -> bf16 ----------
// d = 1024 fixed: 256 threads, one float4 per thread.
__global__ void rownorm_expmap(const float* __restrict__ x,
                               ushort_t* __restrict__ out,
                               const float* __restrict__ cptr) {
  const int d = 1024;
  const int tid = threadIdx.x;
  const int lane = tid & 63, w = tid >> 6;
  __shared__ float red[4];

  const float4* xr = reinterpret_cast<const float4*>(x + (size_t)blockIdx.x * d);
  float4 v = xr[tid];
  float ss = v.x * v.x + v.y * v.y + v.z * v.z + v.w * v.w;
#pragma unroll
  for (int o = 32; o; o >>= 1) ss += __shfl_down(ss, o, 64);
  if (lane == 0) red[w] = ss;
  __syncthreads();
  ss = red[0] + red[1] + red[2] + red[3];

  const float c = *cptr;
  const float sqrtc = sqrtf(c);
  const float norm = fmaxf(sqrtf(ss), 1e-5f);               // expmap0 u_norm clamp
  const float t = tanhf(sqrtc * norm) / (sqrtc * norm);     // expmap scale
  const float en = fmaxf(t * norm, 1e-5f);                  // |expmap0(u)| (project clamp)
  const float maxn = (1.0f - 4e-3f) / sqrtc;
  const float s = t * (en > maxn ? maxn / en : 1.0f);

  ushort4 o = make_ushort4(f32_to_bf16(v.x * s), f32_to_bf16(v.y * s),
                           f32_to_bf16(v.z * s), f32_to_bf16(v.w * s));
  reinterpret_cast<ushort4*>(out + (size_t)blockIdx.x * d)[tid] = o;
}

// ---------------- fp32 -> bf16 elementwise (for W) -------------------------
__global__ void cvt_bf16(const float* __restrict__ in, ushort_t* __restrict__ out,
                         int n4) {
  int i = blockIdx.x * blockDim.x + threadIdx.x;
  if (i >= n4) return;
  float4 v = reinterpret_cast<const float4*>(in)[i];
  ushort4 o = make_ushort4(f32_to_bf16(v.x), f32_to_bf16(v.y),
                           f32_to_bf16(v.z), f32_to_bf16(v.w));
  reinterpret_cast<ushort4*>(out)[i] = o;
}

// ---------------- C = A (MxK) * B^T (B is NxK row-major), bf16 in ----------
// 128x128 tile, BK=32, 256 threads = 4 waves in 2x2, each wave 64x64 (4x4 MFMA accs).
// Staging via global_load_lds width=16 (wave-uniform LDS base + lane*16).
template <bool BF16_OUT>
__global__ void gemm_bt(const ushort_t* __restrict__ A,
                        const ushort_t* __restrict__ B,
                        ushort_t* __restrict__ Cb, float* __restrict__ Cf,
                        int K, int N) {
  __shared__ __align__(16) ushort_t As[128 * 32];
  __shared__ __align__(16) ushort_t Bs[128 * 32];

  const int tid = threadIdx.x;
  const int w = tid >> 6;
  const int lane = tid & 63;
  const int wr = w >> 1, wc = w & 1;
  const int lane15 = lane & 15;
  const int quad = lane >> 4;

  const size_t rowBase = (size_t)blockIdx.x * 128;
  const size_t colBase = (size_t)blockIdx.y * 128;

  // staging: wave w fills chunks {2w, 2w+1}; chunk = 16 rows x 32 cols (1024B)
  const int srow = lane >> 2;          // 0..15
  const int scolE = (lane & 3) * 8;    // element offset 0,8,16,24
  const ushort_t* Ag = A + (rowBase + (size_t)(w * 32 + srow)) * K + scolE;
  const ushort_t* Bg = B + (colBase + (size_t)(w * 32 + srow)) * K + scolE;
  ushort_t* AsD = &As[(w * 2) * 512];  // wave-uniform
  ushort_t* BsD = &Bs[(w * 2) * 512];

  f32x4 acc[4][4];
#pragma unroll
  for (int i = 0; i < 4; ++i)
#pragma unroll
    for (int j = 0; j < 4; ++j) acc[i][j] = f32x4{0.f, 0.f, 0.f, 0.f};

  for (int k0 = 0; k0 < K; k0 += 32) {
    async_copy16(Ag + k0, AsD);
    async_copy16(Ag + (size_t)16 * K + k0, AsD + 512);
    async_copy16(Bg + k0, BsD);
    async_copy16(Bg + (size_t)16 * K + k0, BsD + 512);
    __syncthreads();

    bf16x8 af[4], bv[4];
#pragma unroll
    for (int i = 0; i < 4; ++i) {
      af[i] = *reinterpret_cast<const bf16x8*>(&As[(wr * 64 + i * 16 + lane15) * 32 + quad * 8]);
      bv[i] = *reinterpret_cast<const bf16x8*>(&Bs[(wc * 64 + i * 16 + lane15) * 32 + quad * 8]);
    }
#pragma unroll
    for (int i = 0; i < 4; ++i)
#pragma unroll
      for (int j = 0; j < 4; ++j)
        acc[i][j] = __builtin_amdgcn_mfma_f32_16x16x32_bf16(af[i], bv[j], acc[i][j], 0, 0, 0);
    __syncthreads();
  }

  // C/D layout: col = lane&15, row = quad*4 + reg
#pragma unroll
  for (int i = 0; i < 4; ++i)
#pragma unroll
    for (int j = 0; j < 4; ++j)
#pragma unroll
      for (int r = 0; r < 4; ++r) {
        size_t row = rowBase + (size_t)(wr * 64 + i * 16 + quad * 4 + r);
        size_t col = colBase + (size_t)(wc * 64 + j * 16 + lane15);
        float val = acc[i][j][r];
        if (BF16_OUT)
          Cb[row * N + col] = f32_to_bf16(val);
        else
          Cf[row * N + col] = val;
      }
}

// ---------------- in-place softmax(row/d) + expmap0 + project --------------
// m = 4096 fixed: 256 threads, 4 float4 per thread.
__global__ void softmax_expmap(float* __restrict__ S,
                               const float* __restrict__ cptr, float invd) {
  const int tid = threadIdx.x;
  const int lane = tid & 63, w = tid >> 6;
  __shared__ float red[4];
  float* rp = S + (size_t)blockIdx.x * 4096;

  float4 v[4];
#pragma unroll
  for (int i = 0; i < 4; ++i) v[i] = reinterpret_cast<float4*>(rp)[i * 256 + tid];

  float mx = -1e30f;
#pragma unroll
  for (int i = 0; i < 4; ++i) {
    v[i].x *= invd; v[i].y *= invd; v[i].z *= invd; v[i].w *= invd;
    mx = fmaxf(mx, fmaxf(fmaxf(v[i].x, v[i].y), fmaxf(v[i].z, v[i].w)));
  }
#pragma unroll
  for (int o = 32; o; o >>= 1) mx = fmaxf(mx, __shfl_down(mx, o, 64));
  if (lane == 0) red[w] = mx;
  __syncthreads();
  mx = fmaxf(fmaxf(red[0], red[1]), fmaxf(red[2], red[3]));
  __syncthreads();

  float sum = 0.f, sq = 0.f;
#pragma unroll
  for (int i = 0; i < 4; ++i) {
    v[i].x = expf(v[i].x - mx); v[i].y = expf(v[i].y - mx);
    v[i].z = expf(v[i].z - mx); v[i].w = expf(v[i].w - mx);
    sum += v[i].x + v[i].y + v[i].z + v[i].w;
    sq += v[i].x * v[i].x + v[i].y * v[i].y + v[i].z * v[i].z + v[i].w * v[i].w;
  }
#pragma unroll
  for (int o = 32; o; o >>= 1) sum += __shfl_down(sum, o, 64);
  if (lane == 0) red[w] = sum;
  __syncthreads();
  sum = red[0] + red[1] + red[2] + red[3];
  __syncthreads();
#pragma unroll
  for (int o = 32; o; o >>= 1) sq += __shfl_down(sq, o, 64);
  if (lane == 0) red[w] = sq;
  __syncthreads();
  sq = red[0] + red[1] + red[2] + red[3];

  const float c = *cptr;
  const float sqrtc = sqrtf(c);
  const float anorm = sqrtf(sq) / sum;            // |attn|
  const float an = fmaxf(anorm, 1e-5f);           // expmap0 clamp
  const float t = tanhf(sqrtc * an) / (sqrtc * an);
  const float pn = fmaxf(t * anorm, 1e-5f);       // |expmap0(attn)| (project clamp)
  const float maxn = (1.0f - 4e-3f) / sqrtc;
  const float g = t * (pn > maxn ? maxn / pn : 1.0f) / sum;

#pragma unroll
  for (int i = 0; i < 4; ++i) {
    v[i].x *= g; v[i].y *= g; v[i].z *= g; v[i].w *= g;
    reinterpret_cast<float4*>(rp)[i * 256 + tid] = v[i];
  }
}

extern "C" void kernel_launch(void* const* d_in, const int* in_sizes, int n_in,
                              void* d_out, int out_size, void* d_ws, size_t ws_size,
                              hipStream_t stream) {
  const float* query = (const float*)d_in[0];
  const float* context = (const float*)d_in[1];
  const float* W = (const float*)d_in[2];
  const float* cptr = (const float*)d_in[3];

  const int d = 1024;
  const int n = in_sizes[0] / d;  // 4096
  const int m = in_sizes[1] / d;  // 4096

  ushort_t* qn = (ushort_t*)d_ws;               // n*d bf16
  ushort_t* cn = qn + (size_t)n * d;            // m*d bf16
  ushort_t* Wb = cn + (size_t)m * d;            // d*d bf16
  ushort_t* qw = Wb + (size_t)d * d;            // n*d bf16
  float* scores = (float*)d_out;                // n*m fp32, softmaxed in place

  rownorm_expmap<<<n, 256, 0, stream>>>(query, qn, cptr);
  rownorm_expmap<<<m, 256, 0, stream>>>(context, cn, cptr);
  cvt_bf16<<<(d * d / 4 + 255) / 256, 256, 0, stream>>>(W, Wb, d * d / 4);
  // qw = qn @ W^T   (gemm_bt: B given row-major [N,K])
  gemm_bt<true><<<dim3(n / 128, d / 128), 256, 0, stream>>>(qn, Wb, qw, nullptr, d, d);
  // scores = qw @ cn^T
  gemm_bt<false><<<dim3(n / 128, m / 128), 256, 0, stream>>>(qw, cn, nullptr, scores, d, m);
  softmax_expmap<<<n, 256, 0, stream>>>(scores, cptr, 1.0f / (float)d);
}